// Round 1
// baseline (2708.577 us; speedup 1.0000x reference)
//
#include <hip/hip_runtime.h>
#include <cstdint>
#include <cstddef>

// ---------------------------------------------------------------------------
// GranMultiHeadAttention: B=8, S=1024, EMB=512, H=8, DK=64  (all f32 in/out)
//
// Staged pipeline (all bf16 MFMA, f32 accumulate):
//  K0: W{q,k,v,p} -> WT bf16 [o][i]
//  K1: X@W+b -> Qs(s,bh,d scaled), Kb(bh,s,d), Vt(bh,d,s)   bf16
//  K2: scores = Q@K^T (per-bh tiles) + Sq@ek^T (per-q tiles) + bias,
//      merged in LDS; per-(row,kchunk) softmax stats; P~=exp(s-Mc) bf16
//  K3: O = sum_c corr_c * (P~@V + P~@ev) ; corr from (Mc,Sc) -> AttnOut bf16
//  K4: AttnOut@Wp+bp -> out f32
// ---------------------------------------------------------------------------

typedef __bf16 bf16x8 __attribute__((ext_vector_type(8)));
typedef float f32x4 __attribute__((ext_vector_type(4)));
typedef unsigned short u16x8 __attribute__((ext_vector_type(8)));
typedef unsigned short u16;

__device__ __forceinline__ u16 f2bf(float f) {
  unsigned int u = __float_as_uint(f);
  return (u16)((u + 0x7fffu + ((u >> 16) & 1u)) >> 16);  // RNE, inputs finite
}

__device__ __forceinline__ bf16x8 ld8(const u16* p) {     // 16B-aligned bf16 frag
  return __builtin_bit_cast(bf16x8, *(const u16x8*)p);
}

__device__ __forceinline__ bf16x8 cvt8(const float* p) {  // 8 contiguous f32 -> bf16x8
  const float4 f1 = *(const float4*)p;
  const float4 f2 = *(const float4*)(p + 4);
  u16x8 u;
  u[0]=f2bf(f1.x); u[1]=f2bf(f1.y); u[2]=f2bf(f1.z); u[3]=f2bf(f1.w);
  u[4]=f2bf(f2.x); u[5]=f2bf(f2.y); u[6]=f2bf(f2.z); u[7]=f2bf(f2.w);
  return __builtin_bit_cast(bf16x8, u);
}

__device__ __forceinline__ bf16x8 gather8(const float* p, int stride) {
  u16x8 u;
#pragma unroll
  for (int j = 0; j < 8; j++) u[j] = f2bf(p[(size_t)j * stride]);
  return __builtin_bit_cast(bf16x8, u);
}

__device__ __forceinline__ f32x4 mfma16(bf16x8 a, bf16x8 b, f32x4 c) {
  return __builtin_amdgcn_mfma_f32_16x16x32_bf16(a, b, c, 0, 0, 0);
}

// ------------------------------- K0: weights -------------------------------
__global__ __launch_bounds__(256) void k0_weights(
    const float* __restrict__ Wq, const float* __restrict__ Wk,
    const float* __restrict__ Wv, const float* __restrict__ Wp,
    u16* __restrict__ WT) {
  const int idx = blockIdx.x * 256 + threadIdx.x;   // 4 * 512 * 512
  const int w = idx >> 18;
  const int rem = idx & 262143;
  const int o = rem >> 9, i = rem & 511;
  const float* W = (w == 0) ? Wq : (w == 1) ? Wk : (w == 2) ? Wv : Wp;
  WT[idx] = f2bf(W[(size_t)i * 512 + o]);           // WT[w][o][i] = W[i][o]
}

// ------------------------------ K1: QKV proj -------------------------------
// grid (128 mtiles, 8 heads, 3 z), block 256 (4 waves, each a 16-row strip)
__global__ __launch_bounds__(256) void k1_proj(
    const float* __restrict__ Xq, const float* __restrict__ Xk,
    const float* __restrict__ Xv, const float* __restrict__ bq,
    const float* __restrict__ bk, const float* __restrict__ bv,
    const u16* __restrict__ WT, u16* __restrict__ Qs, u16* __restrict__ Kb,
    u16* __restrict__ Vt) {
  const int z = blockIdx.z;
  const float* X = (z == 0) ? Xq : (z == 1) ? Xk : Xv;
  const float* bias = (z == 0) ? bq : (z == 1) ? bk : bv;
  const u16* W = WT + (size_t)z * 512 * 512;
  const int mt = blockIdx.x, h = blockIdx.y;
  const int tid = threadIdx.x;
  const int wave = tid >> 6, lane = tid & 63;
  const int lm = lane & 15, quad = lane >> 4;
  const int row0 = mt * 64 + wave * 16;

  f32x4 acc0 = {0.f,0.f,0.f,0.f}, acc1 = {0.f,0.f,0.f,0.f};
  f32x4 acc2 = {0.f,0.f,0.f,0.f}, acc3 = {0.f,0.f,0.f,0.f};
  for (int kk = 0; kk < 512; kk += 32) {
    bf16x8 a = cvt8(X + (size_t)(row0 + lm) * 512 + kk + quad * 8);
    acc0 = mfma16(a, ld8(W + (size_t)(h*64 +  0 + lm)*512 + kk + quad*8), acc0);
    acc1 = mfma16(a, ld8(W + (size_t)(h*64 + 16 + lm)*512 + kk + quad*8), acc1);
    acc2 = mfma16(a, ld8(W + (size_t)(h*64 + 32 + lm)*512 + kk + quad*8), acc2);
    acc3 = mfma16(a, ld8(W + (size_t)(h*64 + 48 + lm)*512 + kk + quad*8), acc3);
  }
  f32x4 acc[4] = {acc0, acc1, acc2, acc3};
#pragma unroll
  for (int n = 0; n < 4; n++) {
#pragma unroll
    for (int r = 0; r < 4; r++) {
      const int row = row0 + quad * 4 + r;         // global (b,s) row
      const int b_ = row >> 10, s = row & 1023;
      const int d = n * 16 + lm;
      const float v = acc[n][r] + bias[h * 64 + d];
      const int bh = b_ * 8 + h;
      if (z == 0)      Qs[(((size_t)s) * 64 + bh) * 64 + d] = f2bf(v * 0.125f);
      else if (z == 1) Kb[(((size_t)bh) * 1024 + s) * 64 + d] = f2bf(v);
      else             Vt[(((size_t)bh) * 64 + d) * 1024 + s] = f2bf(v);
    }
  }
}

// --------------------------- K2: scores + softmax --------------------------
// grid (4 kchunks, 64 qtiles), block 256. Per block: 16 q x 64 bh x 256 k.
// LDS score tile: [16 q][32 bhl][16 k], bh-stride 17, q-stride 548 (bank pad)
#define SC_QS 548
#define SC_BS 17
__global__ __launch_bounds__(256) void k2_scores(
    const u16* __restrict__ Qs, const u16* __restrict__ Kb,
    const float* __restrict__ EK, const float* __restrict__ BIAS,
    u16* __restrict__ P, float* __restrict__ Mc, float* __restrict__ Sc) {
  const int kc = blockIdx.x;          // 0..3
  const int qt = blockIdx.y;          // 0..63
  const int q0 = qt * 16;
  const int kbase = kc * 256;
  const int tid = threadIdx.x;
  const int wave = tid >> 6, lane = tid & 63;
  const int lm = lane & 15, quad = lane >> 4;

  __shared__ float scb[16 * SC_QS];   // ~35 KB
  __shared__ float mrow[1024];        // rows = q(16) x bh(64)
  __shared__ float srow[1024];

  for (int i = tid; i < 1024; i += 256) { mrow[i] = -1e30f; srow[i] = 0.f; }
  __syncthreads();

  for (int pass = 0; pass < 2; pass++) {
    for (int ks = 0; ks < 256; ks += 16) {
      const int kg = kbase + ks;
      for (int bhh = 0; bhh < 2; bhh++) {
        // --- phase A: QK tiles (M=q16, N=k16, K=64), one tile per bh ---
        for (int t = 0; t < 8; t++) {
          const int bh = bhh * 32 + wave * 8 + t;
          const u16* aq = Qs + (((size_t)(q0 + lm)) * 64 + bh) * 64;
          const u16* bkp = Kb + ((size_t)bh * 1024 + (kg + lm)) * 64;
          f32x4 acc = {0.f,0.f,0.f,0.f};
          acc = mfma16(ld8(aq + quad * 8), ld8(bkp + quad * 8), acc);
          acc = mfma16(ld8(aq + 32 + quad * 8), ld8(bkp + 32 + quad * 8), acc);
          const int bhl = bh - bhh * 32;
#pragma unroll
          for (int r = 0; r < 4; r++)
            scb[(quad * 4 + r) * SC_QS + bhl * SC_BS + lm] = acc[r];
        }
        __syncthreads();
        // --- phase B: edge-bias tiles (M=bh16, N=k16, K=64), per q-row ---
        for (int t = 0; t < 8; t++) {
          const int tileid = wave * 8 + t;
          const int q = tileid >> 1;
          const int bhl0 = (tileid & 1) * 16;
          const u16* aq =
              Qs + (((size_t)(q0 + q)) * 64 + bhh * 32 + bhl0 + lm) * 64;
          const float* be = EK + (((size_t)(q0 + q)) * 1024 + (kg + lm)) * 64;
          f32x4 acc = {0.f,0.f,0.f,0.f};
          acc = mfma16(ld8(aq + quad * 8), cvt8(be + quad * 8), acc);
          acc = mfma16(ld8(aq + 32 + quad * 8), cvt8(be + 32 + quad * 8), acc);
#pragma unroll
          for (int r = 0; r < 4; r++)
            scb[q * SC_QS + (bhl0 + quad * 4 + r) * SC_BS + lm] += acc[r];
        }
        __syncthreads();
        // --- phase C ---
        if (pass == 0) {            // online (max,sumexp) per row
          for (int rr = 0; rr < 2; rr++) {
            const int rl = tid + 256 * rr;           // 0..511
            const int q = rl >> 5, bhl = rl & 31;
            const int bh = bhh * 32 + bhl;
            const int rid = q * 64 + bh;
            const float* bp_ =
                BIAS + (((size_t)(bh >> 3)) * 1024 + q0 + q) * 1024 + kg;
            const float* scr = scb + q * SC_QS + bhl * SC_BS;
            float m_old = mrow[rid], mx = m_old;
            float vals[16];
#pragma unroll
            for (int k = 0; k < 16; k++) {
              float v = scr[k] + bp_[k];
              vals[k] = v;
              mx = fmaxf(mx, v);
            }
            float ss = srow[rid] * __expf(m_old - mx);
#pragma unroll
            for (int k = 0; k < 16; k++) ss += __expf(vals[k] - mx);
            mrow[rid] = mx; srow[rid] = ss;
          }
        } else {                    // write P~ = exp(s - Mc), bf16
          for (int it = 0; it < 32; it++) {
            const int el = it * 256 + tid;           // 0..8191
            const int kk2 = el & 15, rl = el >> 4;
            const int q = rl >> 5, bhl = rl & 31;
            const int bh = bhh * 32 + bhl;
            const float v =
                scb[q * SC_QS + bhl * SC_BS + kk2] +
                BIAS[(((size_t)(bh >> 3)) * 1024 + q0 + q) * 1024 + kg + kk2];
            P[(((size_t)(q0 + q)) * 64 + bh) * 1024 + kg + kk2] =
                f2bf(__expf(v - mrow[q * 64 + bh]));
          }
        }
        __syncthreads();
      }
    }
    if (pass == 0) {
      for (int rr = 0; rr < 4; rr++) {
        const int rid = tid + 256 * rr;
        const int q = rid >> 6, bh = rid & 63;
        Mc[(((size_t)(q0 + q)) * 64 + bh) * 4 + kc] = mrow[rid];
        Sc[(((size_t)(q0 + q)) * 64 + bh) * 4 + kc] = srow[rid];
      }
      __syncthreads();
    }
  }
}

// ------------------- K3: O = sum_c corr_c*(P~@V + P~@ev) -------------------
// grid 256 (4 q-rows each), block 256. o_lds [4 q][64 bh][d], d-stride 33.
__global__ __launch_bounds__(256) void k3_out(
    const u16* __restrict__ P, const u16* __restrict__ Vt,
    const float* __restrict__ EV, const float* __restrict__ Mc,
    const float* __restrict__ Sc, u16* __restrict__ AttnOut) {
  const int q0 = blockIdx.x * 4;
  const int tid = threadIdx.x;
  const int wave = tid >> 6, lane = tid & 63;
  const int lm = lane & 15, quad = lane >> 4;
  __shared__ float o_lds[4 * 64 * 33];   // 33 KB
  __shared__ float corr[4 * 64 * 4];     // [q][bh][chunk]
  {
    const int q = tid >> 6, bh = tid & 63;
    const float* mp = Mc + (((size_t)(q0 + q)) * 64 + bh) * 4;
    const float* sp = Sc + (((size_t)(q0 + q)) * 64 + bh) * 4;
    const float m0 = mp[0], m1 = mp[1], m2 = mp[2], m3 = mp[3];
    const float mf = fmaxf(fmaxf(m0, m1), fmaxf(m2, m3));
    const float e0 = __expf(m0 - mf), e1 = __expf(m1 - mf);
    const float e2 = __expf(m2 - mf), e3 = __expf(m3 - mf);
    const float inv = 1.f / (sp[0]*e0 + sp[1]*e1 + sp[2]*e2 + sp[3]*e3);
    corr[(q * 64 + bh) * 4 + 0] = e0 * inv;
    corr[(q * 64 + bh) * 4 + 1] = e1 * inv;
    corr[(q * 64 + bh) * 4 + 2] = e2 * inv;
    corr[(q * 64 + bh) * 4 + 3] = e3 * inv;
  }
  __syncthreads();

  const u16x8 zu = {0,0,0,0,0,0,0,0};
  const bf16x8 zf = __builtin_bit_cast(bf16x8, zu);

  for (int dh = 0; dh < 2; dh++) {
    // --- phase Ov: P~ @ V. tiles (bh 64 x nth 2); M=q padded 4->16 ---
    for (int t = 0; t < 32; t++) {
      const int tl = wave * 32 + t;
      const int bh = tl >> 1, nth = tl & 1;
      const int d0 = dh * 32 + nth * 16;
      const u16* pbase = P + (((size_t)(q0 + lm)) * 64 + bh) * 1024;
      const u16* vbase = Vt + ((size_t)bh * 64 + d0 + lm) * 1024;
      f32x4 atot = {0.f,0.f,0.f,0.f};
      for (int c = 0; c < 4; c++) {
        f32x4 a = {0.f,0.f,0.f,0.f};
        for (int k0 = c * 256; k0 < (c + 1) * 256; k0 += 32) {
          bf16x8 af = (lm < 4) ? ld8(pbase + k0 + quad * 8) : zf;
          a = mfma16(af, ld8(vbase + k0 + quad * 8), a);
        }
#pragma unroll
        for (int r = 0; r < 4; r++) {
          const int row = quad * 4 + r;
          if (row < 4) atot[r] += corr[(row * 64 + bh) * 4 + c] * a[r];
        }
      }
#pragma unroll
      for (int r = 0; r < 4; r++) {
        const int row = quad * 4 + r;
        if (row < 4) o_lds[(row * 64 + bh) * 33 + nth * 16 + lm] = atot[r];
      }
    }
    __syncthreads();
    // --- phase Oe: P~ @ ev. tiles (q4 x m4 x nth2), M=bh16 ---
    for (int t = 0; t < 8; t++) {
      const int tl = wave * 8 + t;
      const int q = tl >> 3, m4 = (tl >> 1) & 3, nth = tl & 1;
      const int d0 = dh * 32 + nth * 16;
      const u16* pbase = P + (((size_t)(q0 + q)) * 64 + m4 * 16 + lm) * 1024;
      const float* ebase = EV + ((size_t)(q0 + q)) * 1024 * 64 + d0 + lm;
      f32x4 atot = {0.f,0.f,0.f,0.f};
      for (int c = 0; c < 4; c++) {
        f32x4 a = {0.f,0.f,0.f,0.f};
        for (int k0 = c * 256; k0 < (c + 1) * 256; k0 += 32) {
          bf16x8 af = ld8(pbase + k0 + quad * 8);
          bf16x8 bfr = gather8(ebase + ((size_t)(k0 + quad * 8)) * 64, 64);
          a = mfma16(af, bfr, a);
        }
#pragma unroll
        for (int r = 0; r < 4; r++)
          atot[r] += corr[(q * 64 + m4 * 16 + quad * 4 + r) * 4 + c] * a[r];
      }
#pragma unroll
      for (int r = 0; r < 4; r++)
        o_lds[(q * 64 + m4 * 16 + quad * 4 + r) * 33 + nth * 16 + lm] += atot[r];
    }
    __syncthreads();
    // --- write AttnOut bf16 [b*1024+s][h*64+d] ---
    for (int it = 0; it < 32; it++) {
      const int el = it * 256 + tid;           // 0..8191
      const int dl = el & 31, rl = el >> 5;
      const int q = rl >> 6, bh = rl & 63;
      const int b = bh >> 3, h = bh & 7;
      AttnOut[((size_t)(b * 1024 + q0 + q)) * 512 + h * 64 + dh * 32 + dl] =
          f2bf(o_lds[rl * 33 + dl]);
    }
    __syncthreads();
  }
}

// ------------------------------ K4: out proj -------------------------------
__global__ __launch_bounds__(256) void k4_proj(
    const u16* __restrict__ A, const u16* __restrict__ WpT,
    const float* __restrict__ bp, float* __restrict__ out) {
  const int mt = blockIdx.x, nt = blockIdx.y;
  const int tid = threadIdx.x;
  const int wave = tid >> 6, lane = tid & 63;
  const int lm = lane & 15, quad = lane >> 4;
  const int row0 = mt * 64 + wave * 16;
  f32x4 acc0 = {0.f,0.f,0.f,0.f}, acc1 = {0.f,0.f,0.f,0.f};
  f32x4 acc2 = {0.f,0.f,0.f,0.f}, acc3 = {0.f,0.f,0.f,0.f};
  for (int kk = 0; kk < 512; kk += 32) {
    bf16x8 a = ld8(A + (size_t)(row0 + lm) * 512 + kk + quad * 8);
    acc0 = mfma16(a, ld8(WpT + (size_t)(nt*64 +  0 + lm)*512 + kk + quad*8), acc0);
    acc1 = mfma16(a, ld8(WpT + (size_t)(nt*64 + 16 + lm)*512 + kk + quad*8), acc1);
    acc2 = mfma16(a, ld8(WpT + (size_t)(nt*64 + 32 + lm)*512 + kk + quad*8), acc2);
    acc3 = mfma16(a, ld8(WpT + (size_t)(nt*64 + 48 + lm)*512 + kk + quad*8), acc3);
  }
  f32x4 acc[4] = {acc0, acc1, acc2, acc3};
#pragma unroll
  for (int n = 0; n < 4; n++) {
#pragma unroll
    for (int r = 0; r < 4; r++) {
      const int row = row0 + quad * 4 + r;
      const int col = nt * 64 + n * 16 + lm;
      out[(size_t)row * 512 + col] = acc[n][r] + bp[col];
    }
  }
}

// ------------------------------- launcher ----------------------------------
extern "C" void kernel_launch(void* const* d_in, const int* in_sizes, int n_in,
                              void* d_out, int out_size, void* d_ws,
                              size_t ws_size, hipStream_t stream) {
  const float* queries   = (const float*)d_in[0];
  const float* keys      = (const float*)d_in[1];
  const float* values    = (const float*)d_in[2];
  const float* edges_key = (const float*)d_in[3];
  const float* edges_val = (const float*)d_in[4];
  const float* attn_bias = (const float*)d_in[5];
  const float* Wq = (const float*)d_in[6];
  const float* bq = (const float*)d_in[7];
  const float* Wk = (const float*)d_in[8];
  const float* bk = (const float*)d_in[9];
  const float* Wv = (const float*)d_in[10];
  const float* bv = (const float*)d_in[11];
  const float* Wp = (const float*)d_in[12];
  const float* bp = (const float*)d_in[13];

  char* ws = (char*)d_ws;
  // offsets (bytes)
  const size_t OFF_WT  = 0;                         // 4*512*512*2 = 2 MB
  const size_t OFF_QS  = OFF_WT  + (size_t)4*512*512*2;
  const size_t OFF_KB  = OFF_QS  + (size_t)1024*64*64*2;     // 8 MB each
  const size_t OFF_VT  = OFF_KB  + (size_t)1024*64*64*2;
  const size_t OFF_P   = OFF_VT  + (size_t)1024*64*64*2;
  const size_t OFF_MC  = OFF_P   + (size_t)1024*64*1024*2;   // P: 128 MB
  const size_t OFF_SC  = OFF_MC  + (size_t)1024*64*4*4;      // 1 MB
  const size_t OFF_AO  = OFF_SC  + (size_t)1024*64*4*4;

  u16*   WT  = (u16*)(ws + OFF_WT);
  u16*   Qs  = (u16*)(ws + OFF_QS);
  u16*   Kb  = (u16*)(ws + OFF_KB);
  u16*   Vt  = (u16*)(ws + OFF_VT);
  u16*   Pb  = (u16*)(ws + OFF_P);
  float* Mc  = (float*)(ws + OFF_MC);
  float* Sc  = (float*)(ws + OFF_SC);
  u16*   AO  = (u16*)(ws + OFF_AO);

  k0_weights<<<4096, 256, 0, stream>>>(Wq, Wk, Wv, Wp, WT);
  k1_proj<<<dim3(128, 8, 3), 256, 0, stream>>>(queries, keys, values, bq, bk,
                                               bv, WT, Qs, Kb, Vt);
  k2_scores<<<dim3(4, 64), 256, 0, stream>>>(Qs, Kb, edges_key, attn_bias, Pb,
                                             Mc, Sc);
  k3_out<<<256, 256, 0, stream>>>(Pb, Vt, edges_val, Mc, Sc, AO);
  k4_proj<<<dim3(128, 8), 256, 0, stream>>>(AO, WT + (size_t)3*512*512, bp,
                                            (float*)d_out);
}